// Round 18
// baseline (303.217 us; speedup 1.0000x reference)
//
#include <hip/hip_runtime.h>
#include <hip/hip_bf16.h>

using bf16 = __hip_bfloat16;

typedef __attribute__((ext_vector_type(8))) short bf16x8_t;   // 8 bf16 in 4 VGPRs
typedef __attribute__((ext_vector_type(4))) float f32x4_t;

static __device__ __forceinline__ float b2f(bf16 v) { return __bfloat162float(v); }

// pack two fp32 -> 2 bf16 (RNE) via v_cvt_pk_bf16_f32
static __device__ __forceinline__ unsigned pk2(float a, float b) {
    __hip_bfloat162 h = __float22bfloat162_rn(make_float2(a, b));
    return *reinterpret_cast<unsigned*>(&h);
}
static __device__ __forceinline__ float lo16f(unsigned u) { return __uint_as_float(u << 16); }
static __device__ __forceinline__ float hi16f(unsigned u) { return __uint_as_float(u & 0xFFFF0000u); }

// log2(e)/4 : folds 1/sqrt(DH) and exp->exp2. Applied at qkv output (fp32).
#define QSCALE 0.36067376022224085f

// ---------------- workspace layout (float offsets) ----------------
// ints: cnt[0,8192) rowptr[8192,16385) fill[16448,24640) ssrc[24640,286784) flag ib[286784]
#define OFF_DIS  286848
#define OFF_BIAS 295040   /* 1152 fp32 */
#define OFF_WB   296192   /* bf16 weights (split hi+lo) */
#define OFF_DSRC 410880   /* fp32 edge weights [262144] */
#define OFF_X    935168   /* bf16 x [8192,64] */
#define OFF_HA   1983744  /* bf16 act [8192,128] */
#define OFF_HB   3032320  /* bf16 act [8192,128] */
#define OFF_BO   4605184  /* fp32 attention out [8192,64] */
#define OFF_QKV  5653760  /* bf16: Qb | Kb | VT */
#define OFF_PERM 6440192  /* int[8192] degree-sorted node permutation */
// total 6448384 floats = 25.79 MB

// weight short-offsets (relative to OFF_WB as bf16*), each region hi plane then lo plane
#define HS_E1 0
#define HS_E2 16384
#define HS_E3 49152
#define HS_E4 81920
#define HS_D1 98304
#define HS_D2 114688
#define HS_D3 147456
#define HS_D4 180224
#define HS_AI 196608
#define HS_AO 221184
#define HS_X  1277952   /* = 2*(OFF_X - OFF_WB), plain bf16 x */

// bias fp32 offsets (relative to OFF_BIAS)
#define BF_E1 0
#define BF_E2 128
#define BF_E3 256
#define BF_E4 384
#define BF_D1 448
#define BF_D2 576
#define BF_D3 704
#define BF_D4 832
#define BF_AI 896
#define BF_AO 1088

// ---------------- input canonicalization (sniff + edge-count fused) ----------------
struct CvtEnt { const void* src; int n; int dst; int mode; int p0; int p1; };
struct CvtTab { CvtEnt e[21]; };

__global__ void k_convert(CvtTab tab, float* __restrict__ fb, bf16* __restrict__ hb,
                          int* __restrict__ flagp, const unsigned short* __restrict__ xb,
                          const int* __restrict__ ei, int E, int* __restrict__ cnt) {
    __shared__ int wsum[4];
    unsigned short wv = xb[threadIdx.x * 2];
    int ex = (wv >> 7) & 0xFF;
    int mn = wv & 0x7F;
    int weird = (ex >= 134) || (ex != 0 && ex <= 90) || (ex == 0 && mn != 0);
    unsigned long long bal = __ballot(weird);
    if ((threadIdx.x & 63) == 0) wsum[threadIdx.x >> 6] = (int)__popcll(bal);
    __syncthreads();
    int fl = ((wsum[0] + wsum[1]) + (wsum[2] + wsum[3])) >= 32 ? 1 : 0;   // 1 => fp32
    if (blockIdx.x == 0 && threadIdx.x == 0) *flagp = fl;

    int gi = blockIdx.x * blockDim.x + threadIdx.x;
    if (gi < E) atomicAdd(&cnt[ei[E + gi]], 1);   // fused degree count

    int i = gi;
#pragma unroll 1
    for (int t = 0; t < 21; t++) {
        int n = tab.e[t].n;
        if (i < n) {
            float v = fl ? ((const float*)tab.e[t].src)[i]
                         : b2f(((const bf16*)tab.e[t].src)[i]);
            int mode = tab.e[t].mode, dst = tab.e[t].dst;
            if (mode == 0) {
                fb[dst + i] = v;
            } else if (mode == 4) {
                hb[dst + i] = __float2bfloat16(v);
            } else {
                int idx;
                if (mode == 2) {
                    int dout = tab.e[t].p0;
                    int r = i / dout, c = i - r * dout;
                    idx = ((r >> 3) * dout + c) * 8 + (r & 7);
                } else {
                    int r = i >> 6, c = i & 63;
                    idx = ((c >> 3) * tab.e[t].p1 + r) * 8 + (c & 7);
                }
                bf16 hv = __float2bfloat16(v);
                hb[dst + idx] = hv;
                hb[dst + n + idx] = __float2bfloat16(v - b2f(hv));
            }
            return;
        }
        i -= n;
    }
}

// ---------------- CSR scan + degree-sort permutation (single block) ----------------
__global__ void k_scan(const int* __restrict__ cnt, int* __restrict__ rowptr,
                       int* __restrict__ fill, float* __restrict__ dis,
                       int* __restrict__ perm) {
    __shared__ int sums[256];
    __shared__ int hist[128];
    __shared__ int hbase[128];
    int t = threadIdx.x;
    if (t < 128) hist[t] = 0;
    int base = t * 32;
    int s = 0;
#pragma unroll
    for (int i = 0; i < 32; i++) s += cnt[base + i];
    sums[t] = s;
    __syncthreads();
    for (int off = 1; off < 256; off <<= 1) {
        int v = (t >= off) ? sums[t - off] : 0;
        __syncthreads();
        sums[t] += v;
        __syncthreads();
    }
    int run = (t == 0) ? 0 : sums[t - 1];
#pragma unroll
    for (int i = 0; i < 32; i++) {
        int idx = base + i;
        int c = cnt[idx];
        rowptr[idx] = run;
        fill[idx] = run;
        dis[idx] = rsqrtf((float)(c + 1));
        atomicAdd(&hist[c < 127 ? c : 127], 1);
        run += c;
    }
    if (t == 255) rowptr[8192] = run;
    __syncthreads();
    if (t == 0) {
        int r2 = 0;
        for (int b = 0; b < 128; b++) { hbase[b] = r2; r2 += hist[b]; hist[b] = 0; }
    }
    __syncthreads();
#pragma unroll
    for (int i = 0; i < 32; i++) {
        int idx = base + i;
        int d = cnt[idx] < 127 ? cnt[idx] : 127;
        int r = hbase[d] + atomicAdd(&hist[d], 1);
        perm[r] = idx;
    }
}

__global__ void k_scatter(const int* __restrict__ ei, int E,
                          int* __restrict__ fill, int* __restrict__ ssrc,
                          const float* __restrict__ dis, float* __restrict__ dsrc) {
    int e = blockIdx.x * blockDim.x + threadIdx.x;
    if (e < E) {
        int s = ei[e];
        int pos = atomicAdd(&fill[ei[E + e]], 1);
        ssrc[pos] = s;
        dsrc[pos] = dis[s];
    }
}

// ---------------- shared helpers ----------------
template<int K, int GBF>
static __device__ __forceinline__ float4 grow(const void* H, int row, int fl4) {
    if (GBF) {
        uint2 u = *(const uint2*)((const bf16*)H + (size_t)row * K + fl4);
        float4 v;
        v.x = lo16f(u.x); v.y = hi16f(u.x); v.z = lo16f(u.y); v.w = hi16f(u.y);
        return v;
    }
    return *(const float4*)((const float*)H + (size_t)row * K + fl4);
}

template<int K, int DOUT>
static __device__ __forceinline__ f32x4_t mfma_stage(const float* HsA, const float* HsB,
                                                     int strideF, const bf16* Wb,
                                                     int c0, int lo, int g) {
    constexpr int WPL = K * DOUT;
    const f32x4_t Z = {0.f, 0.f, 0.f, 0.f};
    f32x4_t a = Z;
#pragma unroll
    for (int kk = 0; kk < K / 32; kk++) {
        int ko = kk * 32 + g * 8;
        const float* pa = HsA + lo * strideF + ko;
        float4 x0 = *(const float4*)pa;
        float4 x1 = *(const float4*)(pa + 4);
        if (HsB) {
            const float* pb = HsB + lo * strideF + ko;
            float4 y0 = *(const float4*)pb;
            float4 y1 = *(const float4*)(pb + 4);
            x0.x += y0.x; x0.y += y0.y; x0.z += y0.z; x0.w += y0.w;
            x1.x += y1.x; x1.y += y1.y; x1.z += y1.z; x1.w += y1.w;
        }
        union { unsigned u[4]; bf16x8_t v; } ah, al;
        ah.u[0] = pk2(x0.x, x0.y);
        ah.u[1] = pk2(x0.z, x0.w);
        ah.u[2] = pk2(x1.x, x1.y);
        ah.u[3] = pk2(x1.z, x1.w);
        al.u[0] = pk2(x0.x - lo16f(ah.u[0]), x0.y - hi16f(ah.u[0]));
        al.u[1] = pk2(x0.z - lo16f(ah.u[1]), x0.w - hi16f(ah.u[1]));
        al.u[2] = pk2(x1.x - lo16f(ah.u[2]), x1.y - hi16f(ah.u[2]));
        al.u[3] = pk2(x1.z - lo16f(ah.u[3]), x1.w - hi16f(ah.u[3]));
        size_t wi = (size_t)((kk * 4 + g) * DOUT + c0 + lo) * 8;
        bf16x8_t wh = *(const bf16x8_t*)(Wb + wi);
        bf16x8_t wl = *(const bf16x8_t*)(Wb + WPL + wi);
        a = __builtin_amdgcn_mfma_f32_16x16x32_bf16(ah.v, wh, a, 0, 0, 0);
        a = __builtin_amdgcn_mfma_f32_16x16x32_bf16(al.v, wh, a, 0, 0, 0);
        a = __builtin_amdgcn_mfma_f32_16x16x32_bf16(ah.v, wl, a, 0, 0, 0);
    }
    return a;
}

// ---------------- FUSED GCN layer (degree-sorted node assignment via perm) ----------
template<int K, int DOUT, int RELU, int BS, int GBF>
__global__ void __launch_bounds__(BS)
k_fused(const void* __restrict__ H, const int* __restrict__ rowptr,
        const int* __restrict__ ssrc, const float* __restrict__ dsrc,
        const float* __restrict__ dis, const int* __restrict__ perm,
        const bf16* __restrict__ Wb,
        const float* __restrict__ bias, const bf16* __restrict__ residB,
        bf16* __restrict__ outB, void* __restrict__ outAny, int outOff,
        const int* __restrict__ flagp) {
    constexpr int LPR = K / 4;
    constexpr int SPN = (BS / LPR) / 16;
    constexpr int PADK = K + 4;
    __shared__ float Hs[SPN][16][PADK];

    int tid = threadIdx.x;
    int gp = tid / LPR;
    int li = tid - gp * LPR;
    int fl4 = li * 4;
    int nl = gp / SPN;
    int st = gp - nl * SPN;
    int node = perm[blockIdx.x * 16 + nl];

    float di = dis[node];
    int e0 = rowptr[node], e1 = rowptr[node + 1];
    float4 acc = {0.f, 0.f, 0.f, 0.f};
    if (st == 0) {
        float dii = di * di;
        float4 sv = grow<K, GBF>(H, node, fl4);
        acc.x = sv.x * dii; acc.y = sv.y * dii; acc.z = sv.z * dii; acc.w = sv.w * dii;
    }
    int e = e0 + st;
    for (; e + 3 * SPN < e1; e += 4 * SPN) {
        int s0 = ssrc[e], s1 = ssrc[e + SPN], s2 = ssrc[e + 2 * SPN], s3 = ssrc[e + 3 * SPN];
        float w0 = dsrc[e] * di, w1 = dsrc[e + SPN] * di;
        float w2 = dsrc[e + 2 * SPN] * di, w3 = dsrc[e + 3 * SPN] * di;
        float4 v0 = grow<K, GBF>(H, s0, fl4);
        float4 v1 = grow<K, GBF>(H, s1, fl4);
        float4 v2 = grow<K, GBF>(H, s2, fl4);
        float4 v3 = grow<K, GBF>(H, s3, fl4);
        acc.x += v0.x * w0; acc.y += v0.y * w0; acc.z += v0.z * w0; acc.w += v0.w * w0;
        acc.x += v1.x * w1; acc.y += v1.y * w1; acc.z += v1.z * w1; acc.w += v1.w * w1;
        acc.x += v2.x * w2; acc.y += v2.y * w2; acc.z += v2.z * w2; acc.w += v2.w * w2;
        acc.x += v3.x * w3; acc.y += v3.y * w3; acc.z += v3.z * w3; acc.w += v3.w * w3;
    }
    for (; e < e1; e += SPN) {
        int sv = ssrc[e];
        float wgt = dsrc[e] * di;
        float4 v = grow<K, GBF>(H, sv, fl4);
        acc.x += v.x * wgt; acc.y += v.y * wgt; acc.z += v.z * wgt; acc.w += v.w * wgt;
    }
    *(float4*)&Hs[st][nl][fl4] = acc;
    __syncthreads();

    int w = tid >> 6, lane = tid & 63;
    int lo = lane & 15, g = lane >> 4;
    if (w < DOUT / 16) {
        int c0 = w * 16;
        f32x4_t a = mfma_stage<K, DOUT>(&Hs[0][0][0], SPN == 2 ? &Hs[1][0][0] : nullptr,
                                        PADK, Wb, c0, lo, g);
        float bs = bias[c0 + lo];
        int col = c0 + lo;
#pragma unroll
        for (int r = 0; r < 4; r++) {
            float v = a[r] + bs;
            if (RELU) v = fmaxf(v, 0.f);
            int gnode = perm[blockIdx.x * 16 + 4 * g + r];
            size_t o = (size_t)gnode * DOUT + col;
            if (residB) v += b2f(residB[o]);
            if (outB) outB[o] = __float2bfloat16(v);
            if (outAny) {
                if (*flagp) ((float*)outAny)[(size_t)outOff + o] = v;
                else        ((bf16*)outAny)[(size_t)outOff + o] = __float2bfloat16(v);
            }
        }
    }
}

// ---------------- FUSED e4 + qkv ----------------
__global__ void __launch_bounds__(1024)
k_fused_qkv(const bf16* __restrict__ H, const int* __restrict__ rowptr,
            const int* __restrict__ ssrc, const float* __restrict__ dsrc,
            const float* __restrict__ dis, const int* __restrict__ perm,
            const bf16* __restrict__ We4,
            const float* __restrict__ be4, const bf16* __restrict__ Wai,
            const float* __restrict__ bai, void* __restrict__ outAny, int outOff,
            const int* __restrict__ flagp, bf16* __restrict__ Qkv) {
    constexpr int SPN = 2, PADK = 132;
    __shared__ float Hs[SPN][16][PADK];
    __shared__ float zt[16][68];

    int tid = threadIdx.x;
    int gp = tid >> 5;              // LPR=32
    int li = tid & 31;
    int fl4 = li * 4;
    int nl = gp >> 1;
    int st = gp & 1;
    int node = perm[blockIdx.x * 16 + nl];

    float di = dis[node];
    int e0 = rowptr[node], e1 = rowptr[node + 1];
    float4 acc = {0.f, 0.f, 0.f, 0.f};
    if (st == 0) {
        float dii = di * di;
        float4 sv = grow<128, 1>(H, node, fl4);
        acc.x = sv.x * dii; acc.y = sv.y * dii; acc.z = sv.z * dii; acc.w = sv.w * dii;
    }
    int e = e0 + st;
    for (; e + 3 * SPN < e1; e += 4 * SPN) {
        int s0 = ssrc[e], s1 = ssrc[e + SPN], s2 = ssrc[e + 2 * SPN], s3 = ssrc[e + 3 * SPN];
        float w0 = dsrc[e] * di, w1 = dsrc[e + SPN] * di;
        float w2 = dsrc[e + 2 * SPN] * di, w3 = dsrc[e + 3 * SPN] * di;
        float4 v0 = grow<128, 1>(H, s0, fl4);
        float4 v1 = grow<128, 1>(H, s1, fl4);
        float4 v2 = grow<128, 1>(H, s2, fl4);
        float4 v3 = grow<128, 1>(H, s3, fl4);
        acc.x += v0.x * w0; acc.y += v0.y * w0; acc.z += v0.z * w0; acc.w += v0.w * w0;
        acc.x += v1.x * w1; acc.y += v1.y * w1; acc.z += v1.z * w1; acc.w += v1.w * w1;
        acc.x += v2.x * w2; acc.y += v2.y * w2; acc.z += v2.z * w2; acc.w += v2.w * w2;
        acc.x += v3.x * w3; acc.y += v3.y * w3; acc.z += v3.z * w3; acc.w += v3.w * w3;
    }
    for (; e < e1; e += SPN) {
        int sv = ssrc[e];
        float wgt = dsrc[e] * di;
        float4 v = grow<128, 1>(H, sv, fl4);
        acc.x += v.x * wgt; acc.y += v.y * wgt; acc.z += v.z * wgt; acc.w += v.w * wgt;
    }
    *(float4*)&Hs[st][nl][fl4] = acc;
    __syncthreads();

    int w = tid >> 6, lane = tid & 63;
    int lo = lane & 15, g = lane >> 4;
    if (w < 4) {   // stage 1: z = agg(h3) @ We4 + be4
        int c0 = w * 16;
        f32x4_t a = mfma_stage<128, 64>(&Hs[0][0][0], &Hs[1][0][0], PADK, We4, c0, lo, g);
        float bs = be4[c0 + lo];
        int col = c0 + lo;
#pragma unroll
        for (int r = 0; r < 4; r++) {
            float v = a[r] + bs;
            int row = 4 * g + r;
            zt[row][col] = v;
            int gnode = perm[blockIdx.x * 16 + row];
            size_t o = (size_t)gnode * 64 + col;
            if (*flagp) ((float*)outAny)[(size_t)outOff + o] = v;
            else        ((bf16*)outAny)[(size_t)outOff + o] = __float2bfloat16(v);
        }
    }
    __syncthreads();
    if (w < 12) {  // stage 2: qkv = z @ Wai + bai
        int c0 = w * 16;
        f32x4_t a = mfma_stage<64, 192>(&zt[0][0], nullptr, 68, Wai, c0, lo, g);
        int n = c0 + lo;
        float bs = bai[n];
#pragma unroll
        for (int r = 0; r < 4; r++) {
            float v = a[r] + bs;
            int node2 = perm[blockIdx.x * 16 + 4 * g + r];
            if (n < 64) {
                Qkv[(size_t)node2 * 64 + n] = __float2bfloat16(v * QSCALE);
            } else if (n < 128) {
                Qkv[524288 + (size_t)node2 * 64 + (n - 64)] = __float2bfloat16(v);
            } else {
                Qkv[1048576 + (size_t)(n - 128) * 8192 + node2] = __float2bfloat16(v);
            }
        }
    }
}

// ---------------- FUSED out-proj + d1 ----------------
__global__ void __launch_bounds__(512)
k_fused_d1(const float* __restrict__ Bo, const int* __restrict__ rowptr,
           const int* __restrict__ ssrc, const float* __restrict__ dsrc,
           const float* __restrict__ dis, const int* __restrict__ perm,
           const bf16* __restrict__ Wao,
           const float* __restrict__ bao, const bf16* __restrict__ Wd1,
           const float* __restrict__ bd1, bf16* __restrict__ outB) {
    constexpr int K = 64, SPN = 2, PADK = 68;
    __shared__ float Hs[SPN][16][PADK];
    __shared__ float zt[16][68];
    __shared__ float wsumL[16][2];
    __shared__ float carr[16];

    int tid = threadIdx.x;
    int gp = tid >> 4;              // LPR=16
    int li = tid & 15;
    int fl4 = li * 4;
    int nl = gp >> 1;
    int st = gp & 1;
    int node = perm[blockIdx.x * 16 + nl];

    float di = dis[node];
    int e0 = rowptr[node], e1 = rowptr[node + 1];
    float4 acc = {0.f, 0.f, 0.f, 0.f};
    float ws = 0.f;
    if (st == 0) {
        float dii = di * di;
        float4 sv = *(const float4*)(Bo + (size_t)node * K + fl4);
        acc.x = sv.x * dii; acc.y = sv.y * dii; acc.z = sv.z * dii; acc.w = sv.w * dii;
    }
    int e = e0 + st;
    for (; e + 3 * SPN < e1; e += 4 * SPN) {
        int s0 = ssrc[e], s1 = ssrc[e + SPN], s2 = ssrc[e + 2 * SPN], s3 = ssrc[e + 3 * SPN];
        float w0 = dsrc[e] * di, w1 = dsrc[e + SPN] * di;
        float w2 = dsrc[e + 2 * SPN] * di, w3 = dsrc[e + 3 * SPN] * di;
        ws += ((w0 + w1) + (w2 + w3));
        float4 v0 = *(const float4*)(Bo + (size_t)s0 * K + fl4);
        float4 v1 = *(const float4*)(Bo + (size_t)s1 * K + fl4);
        float4 v2 = *(const float4*)(Bo + (size_t)s2 * K + fl4);
        float4 v3 = *(const float4*)(Bo + (size_t)s3 * K + fl4);
        acc.x += v0.x * w0; acc.y += v0.y * w0; acc.z += v0.z * w0; acc.w += v0.w * w0;
        acc.x += v1.x * w1; acc.y += v1.y * w1; acc.z += v1.z * w1; acc.w += v1.w * w1;
        acc.x += v2.x * w2; acc.y += v2.y * w2; acc.z += v2.z * w2; acc.w += v2.w * w2;
        acc.x += v3.x * w3; acc.y += v3.y * w3; acc.z += v3.z * w3; acc.w += v3.w * w3;
    }
    for (; e < e1; e += SPN) {
        int sv = ssrc[e];
        float wgt = dsrc[e] * di;
        ws += wgt;
        float4 v = *(const float4*)(Bo + (size_t)sv * K + fl4);
        acc.x += v.x * wgt; acc.y += v.y * wgt; acc.z += v.z * wgt; acc.w += v.w * wgt;
    }
    *(float4*)&Hs[st][nl][fl4] = acc;
    if (li == 0) wsumL[nl][st] = ws;
    __syncthreads();
    if (tid < 16) {
        float d2 = dis[perm[blockIdx.x * 16 + tid]];
        carr[tid] = d2 * d2 + wsumL[tid][0] + wsumL[tid][1];
    }
    __syncthreads();

    int w = tid >> 6, lane = tid & 63;
    int lo = lane & 15, g = lane >> 4;
    if (w < 4) {
        int c0 = w * 16;
        f32x4_t a = mfma_stage<64, 64>(&Hs[0][0][0], &Hs[1][0][0], PADK, Wao, c0, lo, g);
        int col = c0 + lo;
        float bs = bao[col];
#pragma unroll
        for (int r = 0; r < 4; r++) {
            int row = 4 * g + r;
            zt[row][col] = a[r] + carr[row] * bs;
        }
    }
    __syncthreads();
    {
        int c0 = w * 16;
        f32x4_t a = mfma_stage<64, 128>(&zt[0][0], nullptr, 68, Wd1, c0, lo, g);
        int col = c0 + lo;
        float bs = bd1[col];
#pragma unroll
        for (int r = 0; r < 4; r++) {
            float v = fmaxf(a[r] + bs, 0.f);
            int gnode = perm[blockIdx.x * 16 + 4 * g + r];
            outB[(size_t)gnode * 128 + col] = __float2bfloat16(v);
        }
    }
}

// ---------------- MFMA flash attention (R11-proven) ----------------
__global__ void __launch_bounds__(512)
k_flash(const bf16* __restrict__ Qb, const bf16* __restrict__ Kb,
        const bf16* __restrict__ VT, float* __restrict__ Bo) {
    __shared__ unsigned short plds[8][2][16][40];
    __shared__ float redo[8][2][16][16];
    __shared__ float redl[8][2][16];
    int w = threadIdx.x >> 6;
    int lane = threadIdx.x & 63;
    int lo = lane & 15;
    int g = lane >> 4;
    int qt = blockIdx.x & 255;
    int h = blockIdx.x >> 8;
    int q0 = qt * 32;
    int m0base = w * 1024;

    const f32x4_t Z = {0.f, 0.f, 0.f, 0.f};
    bf16x8_t zf;
#pragma unroll
    for (int i = 0; i < 8; i++) zf[i] = 0;

    bf16x8_t qf[2];
#pragma unroll
    for (int s = 0; s < 2; s++) {
        if (g < 2) qf[s] = *(const bf16x8_t*)(Qb + (size_t)(q0 + s * 16 + lo) * 64 + h * 16 + g * 8);
        else       qf[s] = zf;
    }

    f32x4_t oacc[2] = {Z, Z};
    float lr[2] = {0.f, 0.f};
    const bf16* kbase = Kb + h * 16 + g * 8;
    const bf16* vbase = VT + (size_t)(h * 16 + lo) * 8192;

    for (int t = 0; t < 32; t++) {
        int m0 = m0base + t * 32;
        bf16x8_t kf0 = zf, kf1 = zf;
        if (g < 2) {
            kf0 = *(const bf16x8_t*)(kbase + (size_t)m0 * 64);
            kf1 = *(const bf16x8_t*)(kbase + (size_t)(m0 + 16) * 64);
        }
        bf16x8_t vt = *(const bf16x8_t*)(vbase + m0 + 8 * g);
#pragma unroll
        for (int s = 0; s < 2; s++) {
            f32x4_t s0 = __builtin_amdgcn_mfma_f32_16x16x32_bf16(kf0, qf[s], Z, 0, 0, 0);
            f32x4_t s1 = __builtin_amdgcn_mfma_f32_16x16x32_bf16(kf1, qf[s], Z, 0, 0, 0);
            float p0 = __builtin_amdgcn_exp2f(s0[0]);
            float p1 = __builtin_amdgcn_exp2f(s0[1]);
            float p2 = __builtin_amdgcn_exp2f(s0[2]);
            float p3 = __builtin_amdgcn_exp2f(s0[3]);
            float p4 = __builtin_amdgcn_exp2f(s1[0]);
            float p5 = __builtin_amdgcn_exp2f(s1[1]);
            float p6 = __builtin_amdgcn_exp2f(s1[2]);
            float p7 = __builtin_amdgcn_exp2f(s1[3]);
            lr[s] += (((p0 + p1) + (p2 + p3)) + ((p4 + p5) + (p6 + p7)));
            unsigned* dst0 = (unsigned*)&plds[w][s][lo][4 * g];
            dst0[0] = pk2(p0, p1);
            dst0[1] = pk2(p2, p3);
            unsigned* dst1 = (unsigned*)&plds[w][s][lo][16 + 4 * g];
            dst1[0] = pk2(p4, p5);
            dst1[1] = pk2(p6, p7);
            bf16x8_t pf = *(const bf16x8_t*)&plds[w][s][lo][8 * g];
            oacc[s] = __builtin_amdgcn_mfma_f32_16x16x32_bf16(vt, pf, oacc[s], 0, 0, 0);
        }
    }
#pragma unroll
    for (int s = 0; s < 2; s++) {
        float l = lr[s];
        l += __shfl_xor(l, 16);
        l += __shfl_xor(l, 32);
        *(f32x4_t*)&redo[w][s][lo][4 * g] = oacc[s];
        if (g == 0) redl[w][s][lo] = l;
    }
    __syncthreads();
    int tid = threadIdx.x;
    int s2 = tid >> 8, q2 = (tid >> 4) & 15, d2 = tid & 15;
    float o = 0.f, l = 0.f;
#pragma unroll
    for (int ww = 0; ww < 8; ww++) {
        o += redo[ww][s2][q2][d2];
        l += redl[ww][s2][q2];
    }
    Bo[(size_t)(q0 + s2 * 16 + q2) * 64 + h * 16 + d2] = o / l;
}

// ---------------- launch ----------------
extern "C" void kernel_launch(void* const* d_in, const int* in_sizes, int n_in,
                              void* d_out, int out_size, void* d_ws, size_t ws_size,
                              hipStream_t stream) {
    int E = in_sizes[1] / 2;
    const int* ei = (const int*)d_in[1];

    int*   ib = (int*)d_ws;
    float* fb = (float*)d_ws;
    int* cnt    = ib;
    int* rowptr = ib + 8192;
    int* fill   = ib + 16448;
    int* ssrc   = ib + 24640;
    int* flagp  = ib + 286784;
    float* dis  = fb + OFF_DIS;
    float* Bias = fb + OFF_BIAS;
    bf16*  Wb   = (bf16*)(fb + OFF_WB);
    float* dsrc = fb + OFF_DSRC;
    bf16*  Xb   = (bf16*)(fb + OFF_X);
    bf16*  HAb  = (bf16*)(fb + OFF_HA);
    bf16*  HBb  = (bf16*)(fb + OFF_HB);
    float* Bo   = fb + OFF_BO;
    bf16*  Qkv  = (bf16*)(fb + OFF_QKV);
    int*   perm = ib + OFF_PERM;

    dim3 b1024(1024), b512(512), b256(256);
    int eb = (E + 255) / 256;

    CvtTab tab;
    auto ent = [&](int i, const void* s, int n, int dst, int mode, int p0, int p1) {
        tab.e[i] = CvtEnt{s, n, dst, mode, p0, p1};
    };
    ent(0,  d_in[0],  524288, HS_X, 4, 0, 0);
    ent(1,  d_in[2],  8192,  HS_E1, 2, 128, 0);
    ent(2,  d_in[3],  128,   OFF_BIAS + BF_E1, 0, 0, 0);
    ent(3,  d_in[4],  16384, HS_E2, 2, 128, 0);
    ent(4,  d_in[5],  128,   OFF_BIAS + BF_E2, 0, 0, 0);
    ent(5,  d_in[6],  16384, HS_E3, 2, 128, 0);
    ent(6,  d_in[7],  128,   OFF_BIAS + BF_E3, 0, 0, 0);
    ent(7,  d_in[8],  8192,  HS_E4, 2, 64, 0);
    ent(8,  d_in[9],  64,    OFF_BIAS + BF_E4, 0, 0, 0);
    ent(9,  d_in[10], 8192,  HS_D1, 2, 128, 0);
    ent(10, d_in[11], 128,   OFF_BIAS + BF_D1, 0, 0, 0);
    ent(11, d_in[12], 16384, HS_D2, 2, 128, 0);
    ent(12, d_in[13], 128,   OFF_BIAS + BF_D2, 0, 0, 0);
    ent(13, d_in[14], 16384, HS_D3, 2, 128, 0);
    ent(14, d_in[15], 128,   OFF_BIAS + BF_D3, 0, 0, 0);
    ent(15, d_in[16], 8192,  HS_D4, 2, 64, 0);
    ent(16, d_in[17], 64,    OFF_BIAS + BF_D4, 0, 0, 0);
    ent(17, d_in[18], 12288, HS_AI, 3, 0, 192);
    ent(18, d_in[19], 192,   OFF_BIAS + BF_AI, 0, 0, 0);
    ent(19, d_in[20], 4096,  HS_AO, 3, 0, 64);
    ent(20, d_in[21], 64,    OFF_BIAS + BF_AO, 0, 0, 0);

    hipMemsetAsync(cnt, 0, 8192 * sizeof(int), stream);
    k_convert<<<dim3(2501), b256, 0, stream>>>(tab, fb, Wb, flagp,
                                               (const unsigned short*)d_in[0], ei, E, cnt);
    k_scan<<<dim3(1), b256, 0, stream>>>(cnt, rowptr, fill, dis, perm);
    k_scatter<<<dim3(eb), b256, 0, stream>>>(ei, E, fill, ssrc, dis, dsrc);

    dim3 g512(512), g1024(1024);

    // encoder (bf16 gathers, degree-sorted blocks)
    k_fused<64, 128, 1, 512, 1><<<g512, b512, 0, stream>>>(Xb, rowptr, ssrc, dsrc, dis, perm,
        Wb + HS_E1, Bias + BF_E1, nullptr, HAb, nullptr, 0, flagp);
    k_fused<128, 128, 1, 1024, 1><<<g512, b1024, 0, stream>>>(HAb, rowptr, ssrc, dsrc, dis, perm,
        Wb + HS_E2, Bias + BF_E2, HAb, HBb, nullptr, 0, flagp);
    k_fused<128, 128, 1, 1024, 1><<<g512, b1024, 0, stream>>>(HBb, rowptr, ssrc, dsrc, dis, perm,
        Wb + HS_E3, Bias + BF_E3, HBb, HAb, nullptr, 0, flagp);
    k_fused_qkv<<<g512, b1024, 0, stream>>>(HAb, rowptr, ssrc, dsrc, dis, perm,
        Wb + HS_E4, Bias + BF_E4, Wb + HS_AI, Bias + BF_AI, d_out, 524288, flagp, Qkv);

    // attention
    k_flash<<<g1024, b512, 0, stream>>>(Qkv, Qkv + 524288, Qkv + 1048576, Bo);

    // decoder
    k_fused_d1<<<g512, b512, 0, stream>>>(Bo, rowptr, ssrc, dsrc, dis, perm,
        Wb + HS_AO, Bias + BF_AO, Wb + HS_D1, Bias + BF_D1, HAb);
    k_fused<128, 128, 1, 1024, 1><<<g512, b1024, 0, stream>>>(HAb, rowptr, ssrc, dsrc, dis, perm,
        Wb + HS_D2, Bias + BF_D2, HAb, HBb, nullptr, 0, flagp);
    k_fused<128, 128, 1, 1024, 1><<<g512, b1024, 0, stream>>>(HBb, rowptr, ssrc, dsrc, dis, perm,
        Wb + HS_D3, Bias + BF_D3, HBb, HAb, nullptr, 0, flagp);
    k_fused<128, 64, 0, 1024, 1><<<g512, b1024, 0, stream>>>(HAb, rowptr, ssrc, dsrc, dis, perm,
        Wb + HS_D4, Bias + BF_D4, nullptr, nullptr, d_out, 0, flagp);
}

// Round 19
// 288.622 us; speedup vs baseline: 1.0506x; 1.0506x over previous
//
#include <hip/hip_runtime.h>
#include <hip/hip_bf16.h>

using bf16 = __hip_bfloat16;

typedef __attribute__((ext_vector_type(8))) short bf16x8_t;   // 8 bf16 in 4 VGPRs
typedef __attribute__((ext_vector_type(4))) float f32x4_t;

static __device__ __forceinline__ float b2f(bf16 v) { return __bfloat162float(v); }

// pack two fp32 -> 2 bf16 (RNE) via v_cvt_pk_bf16_f32
static __device__ __forceinline__ unsigned pk2(float a, float b) {
    __hip_bfloat162 h = __float22bfloat162_rn(make_float2(a, b));
    return *reinterpret_cast<unsigned*>(&h);
}
static __device__ __forceinline__ float lo16f(unsigned u) { return __uint_as_float(u << 16); }
static __device__ __forceinline__ float hi16f(unsigned u) { return __uint_as_float(u & 0xFFFF0000u); }

// log2(e)/4 : folds 1/sqrt(DH) and exp->exp2. Applied at qkv output (fp32).
#define QSCALE 0.36067376022224085f

// ---------------- workspace layout (float offsets) ----------------
// ints: cnt[0,8192) rowptr[8192,16385) fill[16448,24640) ssrc[24640,286784) flag ib[286784]
#define OFF_DIS  286848
#define OFF_BIAS 295040   /* 1152 fp32 */
#define OFF_WB   296192   /* bf16 weights (split hi+lo) */
#define OFF_DSRC 410880   /* fp32 edge weights [262144] */
#define OFF_X    935168   /* bf16 x [8192,64] */
#define OFF_HA   1983744  /* bf16 act [8192,128] */
#define OFF_HB   3032320  /* bf16 act [8192,128] */
#define OFF_BO   4605184  /* fp32 attention out [8192,64] */
#define OFF_QKV  5653760  /* bf16: Qb | Kb | VT */
// total 6440192 floats = 25.76 MB

// weight short-offsets (relative to OFF_WB as bf16*), each region hi plane then lo plane
#define HS_E1 0
#define HS_E2 16384
#define HS_E3 49152
#define HS_E4 81920
#define HS_D1 98304
#define HS_D2 114688
#define HS_D3 147456
#define HS_D4 180224
#define HS_AI 196608
#define HS_AO 221184
#define HS_X  1277952   /* = 2*(OFF_X - OFF_WB), plain bf16 x */

// bias fp32 offsets (relative to OFF_BIAS)
#define BF_E1 0
#define BF_E2 128
#define BF_E3 256
#define BF_E4 384
#define BF_D1 448
#define BF_D2 576
#define BF_D3 704
#define BF_D4 832
#define BF_AI 896
#define BF_AO 1088

// ---------------- input canonicalization (sniff + edge-count fused) ----------------
struct CvtEnt { const void* src; int n; int dst; int mode; int p0; int p1; };
struct CvtTab { CvtEnt e[21]; };

__global__ void k_convert(CvtTab tab, float* __restrict__ fb, bf16* __restrict__ hb,
                          int* __restrict__ flagp, const unsigned short* __restrict__ xb,
                          const int* __restrict__ ei, int E, int* __restrict__ cnt) {
    __shared__ int wsum[4];
    unsigned short wv = xb[threadIdx.x * 2];
    int ex = (wv >> 7) & 0xFF;
    int mn = wv & 0x7F;
    int weird = (ex >= 134) || (ex != 0 && ex <= 90) || (ex == 0 && mn != 0);
    unsigned long long bal = __ballot(weird);
    if ((threadIdx.x & 63) == 0) wsum[threadIdx.x >> 6] = (int)__popcll(bal);
    __syncthreads();
    int fl = ((wsum[0] + wsum[1]) + (wsum[2] + wsum[3])) >= 32 ? 1 : 0;   // 1 => fp32
    if (blockIdx.x == 0 && threadIdx.x == 0) *flagp = fl;

    int gi = blockIdx.x * blockDim.x + threadIdx.x;
    if (gi < E) atomicAdd(&cnt[ei[E + gi]], 1);   // fused degree count

    int i = gi;
#pragma unroll 1
    for (int t = 0; t < 21; t++) {
        int n = tab.e[t].n;
        if (i < n) {
            float v = fl ? ((const float*)tab.e[t].src)[i]
                         : b2f(((const bf16*)tab.e[t].src)[i]);
            int mode = tab.e[t].mode, dst = tab.e[t].dst;
            if (mode == 0) {
                fb[dst + i] = v;
            } else if (mode == 4) {
                hb[dst + i] = __float2bfloat16(v);
            } else {
                int idx;
                if (mode == 2) {
                    int dout = tab.e[t].p0;
                    int r = i / dout, c = i - r * dout;
                    idx = ((r >> 3) * dout + c) * 8 + (r & 7);
                } else {
                    int r = i >> 6, c = i & 63;
                    idx = ((c >> 3) * tab.e[t].p1 + r) * 8 + (c & 7);
                }
                bf16 hv = __float2bfloat16(v);
                hb[dst + idx] = hv;
                hb[dst + n + idx] = __float2bfloat16(v - b2f(hv));
            }
            return;
        }
        i -= n;
    }
}

// ---------------- CSR construction ----------------
__global__ void k_scan(const int* __restrict__ cnt, int* __restrict__ rowptr,
                       int* __restrict__ fill, float* __restrict__ dis) {
    __shared__ int sums[256];
    int t = threadIdx.x;
    int base = t * 32;
    int s = 0;
#pragma unroll
    for (int i = 0; i < 32; i++) s += cnt[base + i];
    sums[t] = s;
    __syncthreads();
    for (int off = 1; off < 256; off <<= 1) {
        int v = (t >= off) ? sums[t - off] : 0;
        __syncthreads();
        sums[t] += v;
        __syncthreads();
    }
    int run = (t == 0) ? 0 : sums[t - 1];
#pragma unroll
    for (int i = 0; i < 32; i++) {
        int idx = base + i;
        rowptr[idx] = run;
        fill[idx] = run;
        dis[idx] = rsqrtf((float)(cnt[idx] + 1));
        run += cnt[idx];
    }
    if (t == 255) rowptr[8192] = run;
}

__global__ void k_scatter(const int* __restrict__ ei, int E,
                          int* __restrict__ fill, int* __restrict__ ssrc,
                          const float* __restrict__ dis, float* __restrict__ dsrc) {
    int e = blockIdx.x * blockDim.x + threadIdx.x;
    if (e < E) {
        int s = ei[e];
        int pos = atomicAdd(&fill[ei[E + e]], 1);
        ssrc[pos] = s;
        dsrc[pos] = dis[s];
    }
}

// ---------------- shared helpers ----------------
template<int K, int GBF>
static __device__ __forceinline__ float4 grow(const void* H, int row, int fl4) {
    if (GBF) {
        uint2 u = *(const uint2*)((const bf16*)H + (size_t)row * K + fl4);
        float4 v;
        v.x = lo16f(u.x); v.y = hi16f(u.x); v.z = lo16f(u.y); v.w = hi16f(u.y);
        return v;
    }
    return *(const float4*)((const float*)H + (size_t)row * K + fl4);
}

template<int K, int DOUT>
static __device__ __forceinline__ f32x4_t mfma_stage(const float* HsA, const float* HsB,
                                                     int strideF, const bf16* Wb,
                                                     int c0, int lo, int g) {
    constexpr int WPL = K * DOUT;
    const f32x4_t Z = {0.f, 0.f, 0.f, 0.f};
    f32x4_t a = Z;
#pragma unroll
    for (int kk = 0; kk < K / 32; kk++) {
        int ko = kk * 32 + g * 8;
        const float* pa = HsA + lo * strideF + ko;
        float4 x0 = *(const float4*)pa;
        float4 x1 = *(const float4*)(pa + 4);
        if (HsB) {
            const float* pb = HsB + lo * strideF + ko;
            float4 y0 = *(const float4*)pb;
            float4 y1 = *(const float4*)(pb + 4);
            x0.x += y0.x; x0.y += y0.y; x0.z += y0.z; x0.w += y0.w;
            x1.x += y1.x; x1.y += y1.y; x1.z += y1.z; x1.w += y1.w;
        }
        union { unsigned u[4]; bf16x8_t v; } ah, al;
        ah.u[0] = pk2(x0.x, x0.y);
        ah.u[1] = pk2(x0.z, x0.w);
        ah.u[2] = pk2(x1.x, x1.y);
        ah.u[3] = pk2(x1.z, x1.w);
        al.u[0] = pk2(x0.x - lo16f(ah.u[0]), x0.y - hi16f(ah.u[0]));
        al.u[1] = pk2(x0.z - lo16f(ah.u[1]), x0.w - hi16f(ah.u[1]));
        al.u[2] = pk2(x1.x - lo16f(ah.u[2]), x1.y - hi16f(ah.u[2]));
        al.u[3] = pk2(x1.z - lo16f(ah.u[3]), x1.w - hi16f(ah.u[3]));
        size_t wi = (size_t)((kk * 4 + g) * DOUT + c0 + lo) * 8;
        bf16x8_t wh = *(const bf16x8_t*)(Wb + wi);
        bf16x8_t wl = *(const bf16x8_t*)(Wb + WPL + wi);
        a = __builtin_amdgcn_mfma_f32_16x16x32_bf16(ah.v, wh, a, 0, 0, 0);
        a = __builtin_amdgcn_mfma_f32_16x16x32_bf16(al.v, wh, a, 0, 0, 0);
        a = __builtin_amdgcn_mfma_f32_16x16x32_bf16(ah.v, wl, a, 0, 0, 0);
    }
    return a;
}

// ---------------- FUSED GCN layer: agg(H) in LDS -> MFMA @ W -> bias/relu/resid ----------
template<int K, int DOUT, int RELU, int BS, int GBF>
__global__ void __launch_bounds__(BS)
k_fused(const void* __restrict__ H, const int* __restrict__ rowptr,
        const int* __restrict__ ssrc, const float* __restrict__ dsrc,
        const float* __restrict__ dis, const bf16* __restrict__ Wb,
        const float* __restrict__ bias, const bf16* __restrict__ residB,
        bf16* __restrict__ outB, void* __restrict__ outAny, int outOff,
        const int* __restrict__ flagp) {
    constexpr int LPR = K / 4;
    constexpr int SPN = (BS / LPR) / 16;
    constexpr int PADK = K + 4;
    __shared__ float Hs[SPN][16][PADK];

    int tid = threadIdx.x;
    int gp = tid / LPR;
    int li = tid - gp * LPR;
    int fl4 = li * 4;
    int nl = gp / SPN;
    int st = gp - nl * SPN;
    int node = blockIdx.x * 16 + nl;

    float di = dis[node];
    int e0 = rowptr[node], e1 = rowptr[node + 1];
    float4 acc = {0.f, 0.f, 0.f, 0.f};
    if (st == 0) {
        float dii = di * di;
        float4 sv = grow<K, GBF>(H, node, fl4);
        acc.x = sv.x * dii; acc.y = sv.y * dii; acc.z = sv.z * dii; acc.w = sv.w * dii;
    }
    int e = e0 + st;
    for (; e + 3 * SPN < e1; e += 4 * SPN) {
        int s0 = ssrc[e], s1 = ssrc[e + SPN], s2 = ssrc[e + 2 * SPN], s3 = ssrc[e + 3 * SPN];
        float w0 = dsrc[e] * di, w1 = dsrc[e + SPN] * di;
        float w2 = dsrc[e + 2 * SPN] * di, w3 = dsrc[e + 3 * SPN] * di;
        float4 v0 = grow<K, GBF>(H, s0, fl4);
        float4 v1 = grow<K, GBF>(H, s1, fl4);
        float4 v2 = grow<K, GBF>(H, s2, fl4);
        float4 v3 = grow<K, GBF>(H, s3, fl4);
        acc.x += v0.x * w0; acc.y += v0.y * w0; acc.z += v0.z * w0; acc.w += v0.w * w0;
        acc.x += v1.x * w1; acc.y += v1.y * w1; acc.z += v1.z * w1; acc.w += v1.w * w1;
        acc.x += v2.x * w2; acc.y += v2.y * w2; acc.z += v2.z * w2; acc.w += v2.w * w2;
        acc.x += v3.x * w3; acc.y += v3.y * w3; acc.z += v3.z * w3; acc.w += v3.w * w3;
    }
    for (; e < e1; e += SPN) {
        int sv = ssrc[e];
        float wgt = dsrc[e] * di;
        float4 v = grow<K, GBF>(H, sv, fl4);
        acc.x += v.x * wgt; acc.y += v.y * wgt; acc.z += v.z * wgt; acc.w += v.w * wgt;
    }
    *(float4*)&Hs[st][nl][fl4] = acc;
    __syncthreads();

    int w = tid >> 6, lane = tid & 63;
    int lo = lane & 15, g = lane >> 4;
    if (w < DOUT / 16) {
        int c0 = w * 16;
        f32x4_t a = mfma_stage<K, DOUT>(&Hs[0][0][0], SPN == 2 ? &Hs[1][0][0] : nullptr,
                                        PADK, Wb, c0, lo, g);
        float bs = bias[c0 + lo];
        int col = c0 + lo;
#pragma unroll
        for (int r = 0; r < 4; r++) {
            float v = a[r] + bs;
            if (RELU) v = fmaxf(v, 0.f);
            int gnode = blockIdx.x * 16 + 4 * g + r;
            size_t o = (size_t)gnode * DOUT + col;
            if (residB) v += b2f(residB[o]);
            if (outB) outB[o] = __float2bfloat16(v);
            if (outAny) {
                if (*flagp) ((float*)outAny)[(size_t)outOff + o] = v;
                else        ((bf16*)outAny)[(size_t)outOff + o] = __float2bfloat16(v);
            }
        }
    }
}

// ---------------- FUSED e4 + qkv: agg(h3)@We4+be4 = z -> d_out; then z@Wai+bai -> Qkv ----
__global__ void __launch_bounds__(1024)
k_fused_qkv(const bf16* __restrict__ H, const int* __restrict__ rowptr,
            const int* __restrict__ ssrc, const float* __restrict__ dsrc,
            const float* __restrict__ dis, const bf16* __restrict__ We4,
            const float* __restrict__ be4, const bf16* __restrict__ Wai,
            const float* __restrict__ bai, void* __restrict__ outAny, int outOff,
            const int* __restrict__ flagp, bf16* __restrict__ Qkv) {
    constexpr int SPN = 2, PADK = 132;
    __shared__ float Hs[SPN][16][PADK];
    __shared__ float zt[16][68];

    int tid = threadIdx.x;
    int gp = tid >> 5;              // LPR=32
    int li = tid & 31;
    int fl4 = li * 4;
    int nl = gp >> 1;
    int st = gp & 1;
    int node = blockIdx.x * 16 + nl;

    float di = dis[node];
    int e0 = rowptr[node], e1 = rowptr[node + 1];
    float4 acc = {0.f, 0.f, 0.f, 0.f};
    if (st == 0) {
        float dii = di * di;
        float4 sv = grow<128, 1>(H, node, fl4);
        acc.x = sv.x * dii; acc.y = sv.y * dii; acc.z = sv.z * dii; acc.w = sv.w * dii;
    }
    int e = e0 + st;
    for (; e + 3 * SPN < e1; e += 4 * SPN) {
        int s0 = ssrc[e], s1 = ssrc[e + SPN], s2 = ssrc[e + 2 * SPN], s3 = ssrc[e + 3 * SPN];
        float w0 = dsrc[e] * di, w1 = dsrc[e + SPN] * di;
        float w2 = dsrc[e + 2 * SPN] * di, w3 = dsrc[e + 3 * SPN] * di;
        float4 v0 = grow<128, 1>(H, s0, fl4);
        float4 v1 = grow<128, 1>(H, s1, fl4);
        float4 v2 = grow<128, 1>(H, s2, fl4);
        float4 v3 = grow<128, 1>(H, s3, fl4);
        acc.x += v0.x * w0; acc.y += v0.y * w0; acc.z += v0.z * w0; acc.w += v0.w * w0;
        acc.x += v1.x * w1; acc.y += v1.y * w1; acc.z += v1.z * w1; acc.w += v1.w * w1;
        acc.x += v2.x * w2; acc.y += v2.y * w2; acc.z += v2.z * w2; acc.w += v2.w * w2;
        acc.x += v3.x * w3; acc.y += v3.y * w3; acc.z += v3.z * w3; acc.w += v3.w * w3;
    }
    for (; e < e1; e += SPN) {
        int sv = ssrc[e];
        float wgt = dsrc[e] * di;
        float4 v = grow<128, 1>(H, sv, fl4);
        acc.x += v.x * wgt; acc.y += v.y * wgt; acc.z += v.z * wgt; acc.w += v.w * wgt;
    }
    *(float4*)&Hs[st][nl][fl4] = acc;
    __syncthreads();

    int w = tid >> 6, lane = tid & 63;
    int lo = lane & 15, g = lane >> 4;
    if (w < 4) {   // stage 1: z = agg(h3) @ We4 + be4  (DOUT=64)
        int c0 = w * 16;
        f32x4_t a = mfma_stage<128, 64>(&Hs[0][0][0], &Hs[1][0][0], PADK, We4, c0, lo, g);
        float bs = be4[c0 + lo];
        int col = c0 + lo;
#pragma unroll
        for (int r = 0; r < 4; r++) {
            float v = a[r] + bs;
            int row = 4 * g + r;
            zt[row][col] = v;
            int gnode = blockIdx.x * 16 + row;
            size_t o = (size_t)gnode * 64 + col;
            if (*flagp) ((float*)outAny)[(size_t)outOff + o] = v;
            else        ((bf16*)outAny)[(size_t)outOff + o] = __float2bfloat16(v);
        }
    }
    __syncthreads();
    if (w < 12) {  // stage 2: qkv = z @ Wai + bai  (K=64, DOUT=192)
        int c0 = w * 16;
        f32x4_t a = mfma_stage<64, 192>(&zt[0][0], nullptr, 68, Wai, c0, lo, g);
        int n = c0 + lo;
        float bs = bai[n];
#pragma unroll
        for (int r = 0; r < 4; r++) {
            float v = a[r] + bs;
            int node2 = blockIdx.x * 16 + 4 * g + r;
            if (n < 64) {
                Qkv[(size_t)node2 * 64 + n] = __float2bfloat16(v * QSCALE);
            } else if (n < 128) {
                Qkv[524288 + (size_t)node2 * 64 + (n - 64)] = __float2bfloat16(v);
            } else {
                Qkv[1048576 + (size_t)(n - 128) * 8192 + node2] = __float2bfloat16(v);
            }
        }
    }
}

// ---------------- FUSED out-proj + d1: agg(za) = agg(Bo)@Wao + c*bao; g1 = relu(.@Wd1+bd1) ----
__global__ void __launch_bounds__(512)
k_fused_d1(const float* __restrict__ Bo, const int* __restrict__ rowptr,
           const int* __restrict__ ssrc, const float* __restrict__ dsrc,
           const float* __restrict__ dis, const bf16* __restrict__ Wao,
           const float* __restrict__ bao, const bf16* __restrict__ Wd1,
           const float* __restrict__ bd1, bf16* __restrict__ outB) {
    constexpr int K = 64, SPN = 2, PADK = 68;
    __shared__ float Hs[SPN][16][PADK];
    __shared__ float zt[16][68];
    __shared__ float wsumL[16][2];
    __shared__ float carr[16];

    int tid = threadIdx.x;
    int gp = tid >> 4;              // LPR=16
    int li = tid & 15;
    int fl4 = li * 4;
    int nl = gp >> 1;
    int st = gp & 1;
    int node = blockIdx.x * 16 + nl;

    float di = dis[node];
    int e0 = rowptr[node], e1 = rowptr[node + 1];
    float4 acc = {0.f, 0.f, 0.f, 0.f};
    float ws = 0.f;
    if (st == 0) {
        float dii = di * di;
        float4 sv = *(const float4*)(Bo + (size_t)node * K + fl4);
        acc.x = sv.x * dii; acc.y = sv.y * dii; acc.z = sv.z * dii; acc.w = sv.w * dii;
    }
    int e = e0 + st;
    for (; e + 3 * SPN < e1; e += 4 * SPN) {
        int s0 = ssrc[e], s1 = ssrc[e + SPN], s2 = ssrc[e + 2 * SPN], s3 = ssrc[e + 3 * SPN];
        float w0 = dsrc[e] * di, w1 = dsrc[e + SPN] * di;
        float w2 = dsrc[e + 2 * SPN] * di, w3 = dsrc[e + 3 * SPN] * di;
        ws += ((w0 + w1) + (w2 + w3));
        float4 v0 = *(const float4*)(Bo + (size_t)s0 * K + fl4);
        float4 v1 = *(const float4*)(Bo + (size_t)s1 * K + fl4);
        float4 v2 = *(const float4*)(Bo + (size_t)s2 * K + fl4);
        float4 v3 = *(const float4*)(Bo + (size_t)s3 * K + fl4);
        acc.x += v0.x * w0; acc.y += v0.y * w0; acc.z += v0.z * w0; acc.w += v0.w * w0;
        acc.x += v1.x * w1; acc.y += v1.y * w1; acc.z += v1.z * w1; acc.w += v1.w * w1;
        acc.x += v2.x * w2; acc.y += v2.y * w2; acc.z += v2.z * w2; acc.w += v2.w * w2;
        acc.x += v3.x * w3; acc.y += v3.y * w3; acc.z += v3.z * w3; acc.w += v3.w * w3;
    }
    for (; e < e1; e += SPN) {
        int sv = ssrc[e];
        float wgt = dsrc[e] * di;
        ws += wgt;
        float4 v = *(const float4*)(Bo + (size_t)sv * K + fl4);
        acc.x += v.x * wgt; acc.y += v.y * wgt; acc.z += v.z * wgt; acc.w += v.w * wgt;
    }
    *(float4*)&Hs[st][nl][fl4] = acc;
    if (li == 0) wsumL[nl][st] = ws;
    __syncthreads();
    if (tid < 16) {
        float d2 = dis[blockIdx.x * 16 + tid];
        carr[tid] = d2 * d2 + wsumL[tid][0] + wsumL[tid][1];
    }
    __syncthreads();

    int w = tid >> 6, lane = tid & 63;
    int lo = lane & 15, g = lane >> 4;
    if (w < 4) {   // stage 1: za = agg(Bo) @ Wao + c*bao  (DOUT=64)
        int c0 = w * 16;
        f32x4_t a = mfma_stage<64, 64>(&Hs[0][0][0], &Hs[1][0][0], PADK, Wao, c0, lo, g);
        int col = c0 + lo;
        float bs = bao[col];
#pragma unroll
        for (int r = 0; r < 4; r++) {
            int row = 4 * g + r;
            zt[row][col] = a[r] + carr[row] * bs;
        }
    }
    __syncthreads();
    // stage 2: g1 = relu(za @ Wd1 + bd1)  (K=64, DOUT=128)
    {
        int c0 = w * 16;
        f32x4_t a = mfma_stage<64, 128>(&zt[0][0], nullptr, 68, Wd1, c0, lo, g);
        int col = c0 + lo;
        float bs = bd1[col];
#pragma unroll
        for (int r = 0; r < 4; r++) {
            float v = fmaxf(a[r] + bs, 0.f);
            int gnode = blockIdx.x * 16 + 4 * g + r;
            outB[(size_t)gnode * 128 + col] = __float2bfloat16(v);
        }
    }
}

// ---------------- MFMA flash attention (R11-proven; no unroll) ----------------
__global__ void __launch_bounds__(512)
k_flash(const bf16* __restrict__ Qb, const bf16* __restrict__ Kb,
        const bf16* __restrict__ VT, float* __restrict__ Bo) {
    __shared__ unsigned short plds[8][2][16][40];
    __shared__ float redo[8][2][16][16];
    __shared__ float redl[8][2][16];
    int w = threadIdx.x >> 6;
    int lane = threadIdx.x & 63;
    int lo = lane & 15;
    int g = lane >> 4;
    int qt = blockIdx.x & 255;
    int h = blockIdx.x >> 8;
    int q0 = qt * 32;
    int m0base = w * 1024;

    const f32x4_t Z = {0.f, 0.f, 0.f, 0.f};
    bf16x8_t zf;
#pragma unroll
    for (int i = 0; i < 8; i++) zf[i] = 0;

    bf16x8_t qf[2];
#pragma unroll
    for (int s = 0; s < 2; s++) {
        if (g < 2) qf[s] = *(const bf16x8_t*)(Qb + (size_t)(q0 + s * 16 + lo) * 64 + h * 16 + g * 8);
        else       qf[s] = zf;
    }

    f32x4_t oacc[2] = {Z, Z};
    float lr[2] = {0.f, 0.f};
    const bf16* kbase = Kb + h * 16 + g * 8;
    const bf16* vbase = VT + (size_t)(h * 16 + lo) * 8192;

    for (int t = 0; t < 32; t++) {
        int m0 = m0base + t * 32;
        bf16x8_t kf0 = zf, kf1 = zf;
        if (g < 2) {
            kf0 = *(const bf16x8_t*)(kbase + (size_t)m0 * 64);
            kf1 = *(const bf16x8_t*)(kbase + (size_t)(m0 + 16) * 64);
        }
        bf16x8_t vt = *(const bf16x8_t*)(vbase + m0 + 8 * g);
#pragma unroll
        for (int s = 0; s < 2; s++) {
            f32x4_t s0 = __builtin_amdgcn_mfma_f32_16x16x32_bf16(kf0, qf[s], Z, 0, 0, 0);
            f32x4_t s1 = __builtin_amdgcn_mfma_f32_16x16x32_bf16(kf1, qf[s], Z, 0, 0, 0);
            float p0 = __builtin_amdgcn_exp2f(s0[0]);
            float p1 = __builtin_amdgcn_exp2f(s0[1]);
            float p2 = __builtin_amdgcn_exp2f(s0[2]);
            float p3 = __builtin_amdgcn_exp2f(s0[3]);
            float p4 = __builtin_amdgcn_exp2f(s1[0]);
            float p5 = __builtin_amdgcn_exp2f(s1[1]);
            float p6 = __builtin_amdgcn_exp2f(s1[2]);
            float p7 = __builtin_amdgcn_exp2f(s1[3]);
            lr[s] += (((p0 + p1) + (p2 + p3)) + ((p4 + p5) + (p6 + p7)));
            unsigned* dst0 = (unsigned*)&plds[w][s][lo][4 * g];
            dst0[0] = pk2(p0, p1);
            dst0[1] = pk2(p2, p3);
            unsigned* dst1 = (unsigned*)&plds[w][s][lo][16 + 4 * g];
            dst1[0] = pk2(p4, p5);
            dst1[1] = pk2(p6, p7);
            bf16x8_t pf = *(const bf16x8_t*)&plds[w][s][lo][8 * g];
            oacc[s] = __builtin_amdgcn_mfma_f32_16x16x32_bf16(vt, pf, oacc[s], 0, 0, 0);
        }
    }
#pragma unroll
    for (int s = 0; s < 2; s++) {
        float l = lr[s];
        l += __shfl_xor(l, 16);
        l += __shfl_xor(l, 32);
        *(f32x4_t*)&redo[w][s][lo][4 * g] = oacc[s];
        if (g == 0) redl[w][s][lo] = l;
    }
    __syncthreads();
    int tid = threadIdx.x;
    int s2 = tid >> 8, q2 = (tid >> 4) & 15, d2 = tid & 15;
    float o = 0.f, l = 0.f;
#pragma unroll
    for (int ww = 0; ww < 8; ww++) {
        o += redo[ww][s2][q2][d2];
        l += redl[ww][s2][q2];
    }
    Bo[(size_t)(q0 + s2 * 16 + q2) * 64 + h * 16 + d2] = o / l;
}

// ---------------- launch ----------------
extern "C" void kernel_launch(void* const* d_in, const int* in_sizes, int n_in,
                              void* d_out, int out_size, void* d_ws, size_t ws_size,
                              hipStream_t stream) {
    int E = in_sizes[1] / 2;
    const int* ei = (const int*)d_in[1];

    int*   ib = (int*)d_ws;
    float* fb = (float*)d_ws;
    int* cnt    = ib;
    int* rowptr = ib + 8192;
    int* fill   = ib + 16448;
    int* ssrc   = ib + 24640;
    int* flagp  = ib + 286784;
    float* dis  = fb + OFF_DIS;
    float* Bias = fb + OFF_BIAS;
    bf16*  Wb   = (bf16*)(fb + OFF_WB);
    float* dsrc = fb + OFF_DSRC;
    bf16*  Xb   = (bf16*)(fb + OFF_X);
    bf16*  HAb  = (bf16*)(fb + OFF_HA);
    bf16*  HBb  = (bf16*)(fb + OFF_HB);
    float* Bo   = fb + OFF_BO;
    bf16*  Qkv  = (bf16*)(fb + OFF_QKV);   // Qb | Kb(+524288) | VT(+1048576)

    dim3 b1024(1024), b512(512), b256(256);
    int eb = (E + 255) / 256;

    CvtTab tab;
    auto ent = [&](int i, const void* s, int n, int dst, int mode, int p0, int p1) {
        tab.e[i] = CvtEnt{s, n, dst, mode, p0, p1};
    };
    ent(0,  d_in[0],  524288, HS_X, 4, 0, 0);   // x -> plain bf16
    ent(1,  d_in[2],  8192,  HS_E1, 2, 128, 0);
    ent(2,  d_in[3],  128,   OFF_BIAS + BF_E1, 0, 0, 0);
    ent(3,  d_in[4],  16384, HS_E2, 2, 128, 0);
    ent(4,  d_in[5],  128,   OFF_BIAS + BF_E2, 0, 0, 0);
    ent(5,  d_in[6],  16384, HS_E3, 2, 128, 0);
    ent(6,  d_in[7],  128,   OFF_BIAS + BF_E3, 0, 0, 0);
    ent(7,  d_in[8],  8192,  HS_E4, 2, 64, 0);
    ent(8,  d_in[9],  64,    OFF_BIAS + BF_E4, 0, 0, 0);
    ent(9,  d_in[10], 8192,  HS_D1, 2, 128, 0);
    ent(10, d_in[11], 128,   OFF_BIAS + BF_D1, 0, 0, 0);
    ent(11, d_in[12], 16384, HS_D2, 2, 128, 0);
    ent(12, d_in[13], 128,   OFF_BIAS + BF_D2, 0, 0, 0);
    ent(13, d_in[14], 16384, HS_D3, 2, 128, 0);
    ent(14, d_in[15], 128,   OFF_BIAS + BF_D3, 0, 0, 0);
    ent(15, d_in[16], 8192,  HS_D4, 2, 64, 0);
    ent(16, d_in[17], 64,    OFF_BIAS + BF_D4, 0, 0, 0);
    ent(17, d_in[18], 12288, HS_AI, 3, 0, 192);
    ent(18, d_in[19], 192,   OFF_BIAS + BF_AI, 0, 0, 0);
    ent(19, d_in[20], 4096,  HS_AO, 3, 0, 64);
    ent(20, d_in[21], 64,    OFF_BIAS + BF_AO, 0, 0, 0);

    hipMemsetAsync(cnt, 0, 8192 * sizeof(int), stream);
    k_convert<<<dim3(2501), b256, 0, stream>>>(tab, fb, Wb, flagp,
                                               (const unsigned short*)d_in[0], ei, E, cnt);
    k_scan<<<dim3(1), b256, 0, stream>>>(cnt, rowptr, fill, dis);
    k_scatter<<<dim3(eb), b256, 0, stream>>>(ei, E, fill, ssrc, dis, dsrc);

    dim3 g512(512), g1024(1024);

    // encoder (bf16 gathers)
    k_fused<64, 128, 1, 512, 1><<<g512, b512, 0, stream>>>(Xb, rowptr, ssrc, dsrc, dis,
        Wb + HS_E1, Bias + BF_E1, nullptr, HAb, nullptr, 0, flagp);
    k_fused<128, 128, 1, 1024, 1><<<g512, b1024, 0, stream>>>(HAb, rowptr, ssrc, dsrc, dis,
        Wb + HS_E2, Bias + BF_E2, HAb, HBb, nullptr, 0, flagp);
    k_fused<128, 128, 1, 1024, 1><<<g512, b1024, 0, stream>>>(HBb, rowptr, ssrc, dsrc, dis,
        Wb + HS_E3, Bias + BF_E3, HBb, HAb, nullptr, 0, flagp);
    // e4 + qkv projection fused (z -> d_out[524288:], qkv -> Qkv)
    k_fused_qkv<<<g512, b1024, 0, stream>>>(HAb, rowptr, ssrc, dsrc, dis,
        Wb + HS_E4, Bias + BF_E4, Wb + HS_AI, Bias + BF_AI, d_out, 524288, flagp, Qkv);

    // attention
    k_flash<<<g1024, b512, 0, stream>>>(Qkv, Qkv + 524288, Qkv + 1048576, Bo);

    // decoder: out-proj + d1 fused
    k_fused_d1<<<g512, b512, 0, stream>>>(Bo, rowptr, ssrc, dsrc, dis,
        Wb + HS_AO, Bias + BF_AO, Wb + HS_D1, Bias + BF_D1, HAb);
    k_fused<128, 128, 1, 1024, 1><<<g512, b1024, 0, stream>>>(HAb, rowptr, ssrc, dsrc, dis,
        Wb + HS_D2, Bias + BF_D2, HAb, HBb, nullptr, 0, flagp);
    k_fused<128, 128, 1, 1024, 1><<<g512, b1024, 0, stream>>>(HBb, rowptr, ssrc, dsrc, dis,
        Wb + HS_D3, Bias + BF_D3, HBb, HAb, nullptr, 0, flagp);
    k_fused<128, 64, 0, 1024, 1><<<g512, b1024, 0, stream>>>(HAb, rowptr, ssrc, dsrc, dis,
        Wb + HS_D4, Bias + BF_D4, nullptr, nullptr, d_out, 0, flagp);
}